// Round 15
// baseline (253.270 us; speedup 1.0000x reference)
//
#include <hip/hip_runtime.h>
#include <hip/hip_bf16.h>
#include <math.h>

#define Tn 100
#define Bn 2048

typedef int v2i __attribute__((ext_vector_type(2)));
typedef _Float16 h2v __attribute__((ext_vector_type(2)));

__device__ __forceinline__ float sp_f(float x) {
    // jax.nn.softplus(x) = max(x,0) + log1p(exp(-|x|))
    float e = __expf(-fabsf(x));
    return fmaxf(x, 0.f) + __logf(1.f + e);
}
__device__ __forceinline__ float clamp6(float x) {
    return fminf(fmaxf(x, -6.f), 6.f);
}
__device__ __forceinline__ unsigned int packh2(float a, float b) {
    h2v h; h.x = (_Float16)a; h.y = (_Float16)b;
    return __builtin_bit_cast(unsigned int, h);
}
__device__ __forceinline__ float dot2f(unsigned int a, unsigned int b, float c) {
#if __has_builtin(__builtin_amdgcn_fdot2)
    return __builtin_amdgcn_fdot2(__builtin_bit_cast(h2v, a),
                                  __builtin_bit_cast(h2v, b), c, false);
#else
    h2v ha = __builtin_bit_cast(h2v, a), hb = __builtin_bit_cast(h2v, b);
    return fmaf((float)ha.y, (float)hb.y, fmaf((float)ha.x, (float)hb.x, c));
#endif
}

__device__ __forceinline__ float dpp_xor1(float x) {
    return __int_as_float(__builtin_amdgcn_mov_dpp(__float_as_int(x), 0xB1, 0xF, 0xF, 1));
}
__device__ __forceinline__ float dpp_xor2(float x) {
    return __int_as_float(__builtin_amdgcn_mov_dpp(__float_as_int(x), 0x4E, 0xF, 0xF, 1));
}
__device__ __forceinline__ float dpp_hmirror(float x) {
    return __int_as_float(__builtin_amdgcn_mov_dpp(__float_as_int(x), 0x141, 0xF, 0xF, 1));
}
__device__ __forceinline__ float dpp_ror8(float x) {
    return __int_as_float(__builtin_amdgcn_mov_dpp(__float_as_int(x), 0x128, 0xF, 0xF, 1));
}
template <int OFF>
__device__ __forceinline__ float swz(float x) {
    return __int_as_float(__builtin_amdgcn_ds_swizzle(__float_as_int(x), OFF));
}
__device__ __forceinline__ float xor16_sum(float x) {
#if __has_builtin(__builtin_amdgcn_permlane16_swap)
    v2i r = __builtin_amdgcn_permlane16_swap(__float_as_int(x), __float_as_int(x), false, false);
    return __int_as_float(r[0]) + __int_as_float(r[1]);
#else
    return x + swz<0x401F>(x);
#endif
}
__device__ __forceinline__ float other_half(float x) {
#if __has_builtin(__builtin_amdgcn_permlane32_swap)
    v2i r = __builtin_amdgcn_permlane32_swap(__float_as_int(x), __float_as_int(x), false, false);
    return (__int_as_float(r[0]) + __int_as_float(r[1])) - x;
#else
    return __shfl_xor(x, 32);
#endif
}

__device__ __forceinline__ void rowd2(float* ha, float* hb, const unsigned int* wrow,
                                      unsigned int xa, unsigned int xb) {
#pragma unroll
    for (int q = 0; q < 7; ++q) {
        uint4 wv = *(const uint4*)(wrow + 4 * q);
        ha[4 * q + 0] = dot2f(xa, wv.x, ha[4 * q + 0]);
        hb[4 * q + 0] = dot2f(xb, wv.x, hb[4 * q + 0]);
        ha[4 * q + 1] = dot2f(xa, wv.y, ha[4 * q + 1]);
        hb[4 * q + 1] = dot2f(xb, wv.y, hb[4 * q + 1]);
        ha[4 * q + 2] = dot2f(xa, wv.z, ha[4 * q + 2]);
        hb[4 * q + 2] = dot2f(xb, wv.z, hb[4 * q + 2]);
        ha[4 * q + 3] = dot2f(xa, wv.w, ha[4 * q + 3]);
        hb[4 * q + 3] = dot2f(xb, wv.w, hb[4 * q + 3]);
    }
    uint2 wt = *(const uint2*)(wrow + 28);
    ha[28] = dot2f(xa, wt.x, ha[28]);
    hb[28] = dot2f(xb, wt.x, hb[28]);
    ha[29] = dot2f(xa, wt.y, ha[29]);
    hb[29] = dot2f(xb, wt.y, hb[29]);
}
__device__ __forceinline__ void dot30_2(const float* ha, const float* hb,
                                        const float* wrow, float& ra, float& rb) {
    float a0 = 0.f, a1 = 0.f, b0 = 0.f, b1 = 0.f;
#pragma unroll
    for (int q = 0; q < 7; ++q) {
        float4 wv = *(const float4*)(wrow + 4 * q);
        a0 = fmaf(ha[4 * q + 0], wv.x, a0);
        b0 = fmaf(hb[4 * q + 0], wv.x, b0);
        a1 = fmaf(ha[4 * q + 1], wv.y, a1);
        b1 = fmaf(hb[4 * q + 1], wv.y, b1);
        a0 = fmaf(ha[4 * q + 2], wv.z, a0);
        b0 = fmaf(hb[4 * q + 2], wv.z, b0);
        a1 = fmaf(ha[4 * q + 3], wv.w, a1);
        b1 = fmaf(hb[4 * q + 3], wv.w, b1);
    }
    float2 wt = *(const float2*)(wrow + 28);
    a0 = fmaf(ha[28], wt.x, a0);
    b0 = fmaf(hb[28], wt.x, b0);
    a1 = fmaf(ha[29], wt.y, a1);
    b1 = fmaf(hb[29], wt.y, b1);
    ra = a0 + a1; rb = b0 + b1;
}
__device__ __forceinline__ void dot16p_2(const unsigned int* pa, const unsigned int* pb,
                                         const unsigned int* wrow, float& ra, float& rb) {
    float a0 = 0.f, a1 = 0.f, b0 = 0.f, b1 = 0.f;
#pragma unroll
    for (int q = 0; q < 4; ++q) {
        uint4 wv = *(const uint4*)(wrow + 4 * q);
        a0 = dot2f(pa[4 * q + 0], wv.x, a0);
        b0 = dot2f(pb[4 * q + 0], wv.x, b0);
        a1 = dot2f(pa[4 * q + 1], wv.y, a1);
        b1 = dot2f(pb[4 * q + 1], wv.y, b1);
        a0 = dot2f(pa[4 * q + 2], wv.z, a0);
        b0 = dot2f(pb[4 * q + 2], wv.z, b0);
        a1 = dot2f(pa[4 * q + 3], wv.w, a1);
        b1 = dot2f(pb[4 * q + 3], wv.w, b1);
    }
    ra = a0 + a1; rb = b0 + b1;
}

// ---------------------------------------------------------------- encoder
// (unchanged from round 12/14 best config)
#define ENC_LOAD2(b0, b1, base)                                               \
    _Pragma("unroll")                                                         \
    for (int i = 0; i < 5; ++i) {                                             \
        b0[i] = *(const float2*)(x0 + (base) + 2 * i);                        \
        b1[i] = *(const float2*)(x1 + (base) + 2 * i);                        \
    }
#define ENC_COMP2(b0, b1, pb)                                                 \
    _Pragma("unroll")                                                         \
    for (int i = 0; i < 5; ++i) {                                             \
        unsigned int xa = packh2(b0[i].x, b0[i].y);                           \
        unsigned int xb = packh2(b1[i].x, b1[i].y);                           \
        rowd2(h1a, h1b, &wh1[((pb) + i) * 32], xa, xb);                       \
    }

__global__ __launch_bounds__(256) void enc_kernel(
    const float* __restrict__ xs,
    const float* __restrict__ eW1, const float* __restrict__ eb1,
    const float* __restrict__ eW2, const float* __restrict__ eb2,
    const float* __restrict__ eW3, const float* __restrict__ eb3,
    float* __restrict__ ctx, float* __restrict__ qm, float* __restrict__ qs)
{
    __shared__ __align__(16) unsigned int wh1[75 * 32];
    __shared__ __align__(16) unsigned int wh2[15 * 32];
    __shared__ __align__(16) float wf[555];

    for (int i = threadIdx.x; i < 75 * 30; i += 256) {
        int p = i / 30, j = i % 30;
        wh1[p * 32 + j] = packh2(eW1[(2 * p) * 30 + j], eW1[(2 * p + 1) * 30 + j]);
    }
    for (int i = threadIdx.x; i < 15 * 30; i += 256) {
        int p = i / 30, j = i % 30;
        wh2[p * 32 + j] = packh2(eW2[(2 * p) * 30 + j], eW2[(2 * p + 1) * 30 + j]);
    }
    if (threadIdx.x < 30) wf[threadIdx.x] = eb1[threadIdx.x];
    if (threadIdx.x >= 32 && threadIdx.x < 62) wf[30 + threadIdx.x - 32] = eb2[threadIdx.x - 32];
    for (int i = threadIdx.x; i < 90; i += 256) {
        int o = i / 30, j2 = i % 30;
        wf[60 + o * 32 + j2] = eW3[j2 * 15 + 12 + o];
    }
    for (int i = threadIdx.x; i < 360; i += 256) {
        int o = i / 30, j2 = i % 30;
        wf[156 + o * 32 + j2] = eW3[j2 * 15 + o];
    }
    if (threadIdx.x >= 64 && threadIdx.x < 79) wf[540 + threadIdx.x - 64] = eb3[threadIdx.x - 64];
    __syncthreads();

    int t = threadIdx.x;
    size_t base = (size_t)blockIdx.x * 512;
    size_t s0 = base + t, s1 = base + t + 256;
    const float* x0 = xs + s0 * 150;
    const float* x1 = xs + s1 * 150;

    float h1a[30], h1b[30];
#pragma unroll
    for (int j = 0; j < 30; ++j) { h1a[j] = wf[j]; h1b[j] = h1a[j]; }

    float2 A0[5], A1[5], B0[5], B1[5];
    ENC_LOAD2(A0, A1, 0)
    ENC_LOAD2(B0, B1, 10)
    int fb = 0;
#pragma unroll 1
    for (int it = 0; it < 6; ++it) {
        ENC_COMP2(A0, A1, fb / 2)
        ENC_LOAD2(A0, A1, fb + 20)
        ENC_COMP2(B0, B1, fb / 2 + 5)
        ENC_LOAD2(B0, B1, fb + 30)
        fb += 20;
    }
    ENC_COMP2(A0, A1, 60)
    ENC_LOAD2(A0, A1, 140)
    ENC_COMP2(B0, B1, 65)
    ENC_COMP2(A0, A1, 70)

#pragma unroll
    for (int j = 0; j < 30; ++j) { h1a[j] = sp_f(h1a[j]); h1b[j] = sp_f(h1b[j]); }

    unsigned int p1a[15], p1b[15];
#pragma unroll
    for (int p = 0; p < 15; ++p) {
        p1a[p] = packh2(h1a[2 * p], h1a[2 * p + 1]);
        p1b[p] = packh2(h1b[2 * p], h1b[2 * p + 1]);
    }
    float h2a[30], h2b[30];
#pragma unroll
    for (int j = 0; j < 30; ++j) { h2a[j] = wf[30 + j]; h2b[j] = h2a[j]; }
#pragma unroll
    for (int p = 0; p < 15; ++p)
        rowd2(h2a, h2b, &wh2[p * 32], p1a[p], p1b[p]);
#pragma unroll
    for (int j = 0; j < 30; ++j) { h2a[j] = sp_f(h2a[j]); h2b[j] = sp_f(h2b[j]); }

    float oa3[3], ob3[3];
#pragma unroll
    for (int o = 0; o < 3; ++o) {
        float ra, rb;
        dot30_2(h2a, h2b, &wf[60 + o * 32], ra, rb);
        oa3[o] = wf[540 + 12 + o] + ra;
        ob3[o] = wf[540 + 12 + o] + rb;
    }
    float* cp0 = ctx + s0 * 3;
    cp0[0] = oa3[0]; cp0[1] = oa3[1]; cp0[2] = oa3[2];
    float* cp1 = ctx + s1 * 3;
    cp1[0] = ob3[0]; cp1[1] = ob3[1]; cp1[2] = ob3[2];

    if (blockIdx.x < 4) {
#pragma unroll
        for (int o = 0; o < 12; ++o) {
            float ra, rb;
            dot30_2(h2a, h2b, &wf[156 + o * 32], ra, rb);
            float va = wf[540 + o] + ra, vb = wf[540 + o] + rb;
            if (o < 6) { qm[s0 * 6 + o] = va; qm[s1 * 6 + o] = vb; }
            else       { qs[s0 * 6 + o - 6] = va; qs[s1 * 6 + o - 6] = vb; }
        }
    }
}

// ------------------------------------------------------------------- SDE scan
// 2 CHAINS PER BLOCK: chains (2b, 2b+1) share one 128-thread block (grid 1024,
// 16 waves/CU). Each wave processes both chains per step (independent ILP
// streams); barriers per chain-step HALVE. sRec record (24 floats/step):
// per chain c: [c*12+0..5]=dW, [+6..8]=ctx(k+1), [+9]=pad, [+10]=t, [+11]=dt.
__global__ __launch_bounds__(128, 4) void scan_kernel(
    const float* __restrict__ ts, const float* __restrict__ dWall,
    const float* __restrict__ fW1, const float* __restrict__ fb1,
    const float* __restrict__ fW2, const float* __restrict__ fb2,
    const float* __restrict__ hW1, const float* __restrict__ hb1,
    const float* __restrict__ hW2, const float* __restrict__ hb2,
    const float* __restrict__ gW1, const float* __restrict__ gb1,
    const float* __restrict__ gW2, const float* __restrict__ gb2,
    const float* __restrict__ ctx,
    const float* __restrict__ qm, const float* __restrict__ qs,
    const float* __restrict__ eps0, const float* __restrict__ pm,
    const float* __restrict__ ps,
    float* __restrict__ zsb, float* __restrict__ acc)
{
    int tid = threadIdx.x;
    int lane = tid & 63;
    int b0c = blockIdx.x * 2;          // chain 0 of this block
    bool isA = tid < 64;

    __shared__ float sRec[99 * 24];
    __shared__ float exF[2][2][12];    // [buf][chain][0..5]=fvv, [6..11]=dfh
    __shared__ float exG[2][2][8];     // [buf][chain][0..5]=g

    // ---- bulk staging -------------------------------------------------
    for (int i = tid; i < 99 * 6; i += 128) {          // dW both chains
        int k = i / 6, r = i % 6, c = r / 3, e = r % 3;
        float2 v = *(const float2*)(dWall + ((size_t)k * Bn + b0c + c) * 6 + e * 2);
        *(float2*)&sRec[k * 24 + c * 12 + e * 2] = v;
    }
    for (int i = tid; i < 99 * 6; i += 128) {          // ctx rows k+1
        int k = i / 6, r = i % 6, c = r / 3, e = r % 3;
        sRec[k * 24 + c * 12 + 6 + e] = ctx[((size_t)(k + 1) * Bn + b0c + c) * 3 + e];
    }
    for (int i = tid; i < 99; i += 128) {              // t, dt (both slots)
        float t0 = ts[i], t1 = ts[i + 1];
        sRec[i * 24 + 9]  = 0.f; sRec[i * 24 + 10] = t0; sRec[i * 24 + 11] = t1 - t0;
        sRec[i * 24 + 21] = 0.f; sRec[i * 24 + 22] = t0; sRec[i * 24 + 23] = t1 - t0;
    }

    float z0[6], z1[6];                // wave A state (both chains)
    float zq0 = 0.f, zq1 = 0.f;        // wave B own-dim state
    float wl1[10], b1w, wl2[6], fb2v[6], hb2v[6];
    float gwa[4], gwb[4], gw2v[4], gbb[4], gb2v = 0.f, wselq = 0.f;
    int dL = 0;

    if (isA) {
        bool lower = lane < 32;
        int j = lane & 31;
        int jc = (j < 30) ? j : 29;
        bool jvalid = (j < 30);
#pragma unroll
        for (int i = 0; i < 10; ++i)
            wl1[i] = lower ? fW1[i * 30 + jc] : (i < 7 ? hW1[i * 30 + jc] : 0.f);
        b1w = lower ? fb1[jc] : hb1[jc];
#pragma unroll
        for (int d = 0; d < 6; ++d)
            wl2[d] = jvalid ? (lower ? fW2[jc * 6 + d] : hW2[jc * 6 + d]) : 0.f;
#pragma unroll
        for (int d = 0; d < 6; ++d) { fb2v[d] = fb2[d]; hb2v[d] = hb2[d]; }
#pragma unroll
        for (int d = 0; d < 6; ++d) {
            float m0 = qm[b0c * 6 + d];
            float s0 = __expf(clamp6(qs[b0c * 6 + d]));
            z0[d] = fmaf(s0, eps0[b0c * 6 + d], m0);
            float m1 = qm[(b0c + 1) * 6 + d];
            float s1 = __expf(clamp6(qs[(b0c + 1) * 6 + d]));
            z1[d] = fmaf(s1, eps0[(b0c + 1) * 6 + d], m1);
        }
        if (tid == 0) {                                // rows b0c, b0c+1 contiguous
            float* zp = zsb + (size_t)b0c * 6;
            *(float4*)(zp)     = make_float4(z0[0], z0[1], z0[2], z0[3]);
            *(float4*)(zp + 4) = make_float4(z0[4], z0[5], z1[0], z1[1]);
            *(float4*)(zp + 8) = make_float4(z1[2], z1[3], z1[4], z1[5]);
        }
    } else {
        int dL8 = lane >> 3;
        dL = (dL8 < 6) ? dL8 : 0;
        wselq = (dL8 < 6) ? 0.0625f : 0.f;
        int s = lane & 7;
#pragma unroll
        for (int u = 0; u < 4; ++u) {
            int jj = s + 8 * u;
            bool ok = (dL8 < 6) && (jj < 30);
            gwa[u]  = ok ? gW1[dL * 60 + jj] : 0.f;
            gwb[u]  = ok ? gW1[dL * 60 + 30 + jj] : 0.f;
            gw2v[u] = ok ? gW2[dL * 30 + jj] : 0.f;
            gbb[u]  = ok ? gb1[dL * 30 + jj] : 0.f;
        }
        gb2v = gb2[dL];
        {
            float m0 = qm[b0c * 6 + dL];
            float s0 = __expf(clamp6(qs[b0c * 6 + dL]));
            zq0 = fmaf(s0, eps0[b0c * 6 + dL], m0);
            float m1 = qm[(b0c + 1) * 6 + dL];
            float s1 = __expf(clamp6(qs[(b0c + 1) * 6 + dL]));
            zq1 = fmaf(s1, eps0[(b0c + 1) * 6 + dL], m1);
        }
        if (tid == 64) {
            float klsum = 0.f;
#pragma unroll
            for (int c = 0; c < 2; ++c) {
#pragma unroll
                for (int d = 0; d < 6; ++d) {
                    float m = qm[(b0c + c) * 6 + d];
                    float sq = __expf(clamp6(qs[(b0c + c) * 6 + d]));
                    float spz = __expf(clamp6(ps[d]));
                    float dm = m - pm[d];
                    klsum += __logf(spz / sq) + (sq * sq + dm * dm) / (2.f * spz * spz) - 0.5f;
                }
            }
            atomicAdd(&acc[1], klsum);
        }
    }

    __syncthreads();

    float pacc = 0.f;

    for (int k = 0; k < Tn - 1; ++k) {
        int kb = k & 1;

        if (isA) {
            float4 r0a = *(float4*)&sRec[k * 24];
            float4 r1a = *(float4*)&sRec[k * 24 + 4];
            float4 r2a = *(float4*)&sRec[k * 24 + 8];
            float4 r0b = *(float4*)&sRec[k * 24 + 12];
            float4 r1b = *(float4*)&sRec[k * 24 + 16];
            float4 r2b = *(float4*)&sRec[k * 24 + 20];
            float t = r2a.z, dt = r2a.w;

            // ---- L1 both chains (independent chains -> ILP) -----------
            float a00 = fmaf(t, wl1[0], b1w);
            a00 = fmaf(z0[0], wl1[1], a00);
            a00 = fmaf(z0[1], wl1[2], a00);
            a00 = fmaf(z0[2], wl1[3], a00);
            a00 = fmaf(z0[3], wl1[4], a00);
            float a01 = z0[4] * wl1[5];
            a01 = fmaf(z0[5], wl1[6], a01);
            a01 = fmaf(r1a.z, wl1[7], a01);
            a01 = fmaf(r1a.w, wl1[8], a01);
            a01 = fmaf(r2a.x, wl1[9], a01);
            float a10 = fmaf(t, wl1[0], b1w);
            a10 = fmaf(z1[0], wl1[1], a10);
            a10 = fmaf(z1[1], wl1[2], a10);
            a10 = fmaf(z1[2], wl1[3], a10);
            a10 = fmaf(z1[3], wl1[4], a10);
            float a11 = z1[4] * wl1[5];
            a11 = fmaf(z1[5], wl1[6], a11);
            a11 = fmaf(r1b.z, wl1[7], a11);
            a11 = fmaf(r1b.w, wl1[8], a11);
            a11 = fmaf(r2b.x, wl1[9], a11);
            float hid0 = sp_f(a00 + a01);
            float hid1 = sp_f(a10 + a11);

            float pp0[6], pp1[6];
#pragma unroll
            for (int d = 0; d < 6; ++d) { pp0[d] = hid0 * wl2[d]; pp1[d] = hid1 * wl2[d]; }
#pragma unroll
            for (int d = 0; d < 6; ++d) { pp0[d] += dpp_xor1(pp0[d]); pp1[d] += dpp_xor1(pp1[d]); }
#pragma unroll
            for (int d = 0; d < 6; ++d) { pp0[d] += dpp_xor2(pp0[d]); pp1[d] += dpp_xor2(pp1[d]); }
#pragma unroll
            for (int d = 0; d < 6; ++d) { pp0[d] += dpp_hmirror(pp0[d]); pp1[d] += dpp_hmirror(pp1[d]); }
#pragma unroll
            for (int d = 0; d < 6; ++d) { pp0[d] += dpp_ror8(pp0[d]); pp1[d] += dpp_ror8(pp1[d]); }
#pragma unroll
            for (int d = 0; d < 6; ++d) { pp0[d] = xor16_sum(pp0[d]); pp1[d] = xor16_sum(pp1[d]); }
            float fvv0[6], fvv1[6];
            bool lower = lane < 32;
#pragma unroll
            for (int d = 0; d < 6; ++d) {
                float oth0 = other_half(pp0[d]);
                float fs0 = lower ? pp0[d] : oth0;
                float hs0 = lower ? oth0 : pp0[d];
                fvv0[d] = fs0 + fb2v[d];
                float df0 = fvv0[d] - (hs0 + hb2v[d]);
                float oth1 = other_half(pp1[d]);
                float fs1 = lower ? pp1[d] : oth1;
                float hs1 = lower ? oth1 : pp1[d];
                fvv1[d] = fs1 + fb2v[d];
                float df1 = fvv1[d] - (hs1 + hb2v[d]);
                if (lane == 0) {
                    exF[kb][0][d] = fvv0[d]; exF[kb][0][6 + d] = df0;
                    exF[kb][1][d] = fvv1[d]; exF[kb][1][6 + d] = df1;
                }
            }

            __syncthreads();

            float4 g03a = *(float4*)&exG[kb][0][0];
            float2 g45a = *(float2*)&exG[kb][0][4];
            float4 g03b = *(float4*)&exG[kb][1][0];
            float2 g45b = *(float2*)&exG[kb][1][4];
            float gl0[6] = { g03a.x, g03a.y, g03a.z, g03a.w, g45a.x, g45a.y };
            float gl1[6] = { g03b.x, g03b.y, g03b.z, g03b.w, g45b.x, g45b.y };
            float dwv0[6] = { r0a.x, r0a.y, r0a.z, r0a.w, r1a.x, r1a.y };
            float dwv1[6] = { r0b.x, r0b.y, r0b.z, r0b.w, r1b.x, r1b.y };
#pragma unroll
            for (int d = 0; d < 6; ++d) {
                z0[d] = fmaf(gl0[d], dwv0[d], fmaf(fvv0[d], dt, z0[d]));
                z1[d] = fmaf(gl1[d], dwv1[d], fmaf(fvv1[d], dt, z1[d]));
            }

            if (tid == 0) {                            // rows adjacent -> 3x float4
                float* zp = zsb + ((size_t)(k + 1) * Bn + b0c) * 6;
                *(float4*)(zp)     = make_float4(z0[0], z0[1], z0[2], z0[3]);
                *(float4*)(zp + 4) = make_float4(z0[4], z0[5], z1[0], z1[1]);
                *(float4*)(zp + 8) = make_float4(z1[2], z1[3], z1[4], z1[5]);
            }
        } else {
            float2 tdt = *(float2*)&sRec[k * 24 + 10];
            float t = tdt.x, dt = tdt.y;
            float dwq0 = sRec[k * 24 + dL];
            float dwq1 = sRec[k * 24 + 12 + dL];

            float ga0 = 0.f, ga1 = 0.f;
#pragma unroll
            for (int u = 0; u < 4; ++u) {
                float prec = fmaf(t, gwa[u], gbb[u]);      // shared between chains
                float pre0 = fmaf(zq0, gwb[u], prec);
                float pre1 = fmaf(zq1, gwb[u], prec);
                ga0 = fmaf(sp_f(pre0), gw2v[u], ga0);
                ga1 = fmaf(sp_f(pre1), gw2v[u], ga1);
            }
            ga0 += dpp_xor1(ga0);   ga1 += dpp_xor1(ga1);
            ga0 += dpp_xor2(ga0);   ga1 += dpp_xor2(ga1);
            ga0 += dpp_hmirror(ga0); ga1 += dpp_hmirror(ga1);
            float gacc0 = ga0 + gb2v, gacc1 = ga1 + gb2v;
            float e0 = __expf(-gacc0), e1 = __expf(-gacc1);
            float rg0 = 1.f + e0, rg1 = 1.f + e1;
            float gval0 = __builtin_amdgcn_rcpf(rg0);
            float gval1 = __builtin_amdgcn_rcpf(rg1);
            if ((lane & 7) == 0 && (lane >> 3) < 6) {
                exG[kb][0][dL] = gval0;
                exG[kb][1][dL] = gval1;
            }

            __syncthreads();

            float fq0  = exF[kb][0][dL];
            float dfq0 = exF[kb][0][6 + dL];
            float fq1  = exF[kb][1][dL];
            float dfq1 = exF[kb][1][6 + dL];
            float u0 = dfq0 * rg0, u1 = dfq1 * rg1;
            pacc = fmaf(wselq * dt, fmaf(u0, u0, u1 * u1), pacc);
            zq0 = fmaf(gval0, dwq0, fmaf(fq0, dt, zq0));
            zq1 = fmaf(gval1, dwq1, fmaf(fq1, dt, zq1));
        }
    }
    if (!isA) {
#pragma unroll
        for (int mm = 1; mm <= 32; mm <<= 1) pacc += __shfl_xor(pacc, mm);
        if (tid == 64) atomicAdd(&acc[2], pacc);
    }
}

// ------------------------------------------------------ decoder + likelihood
// (unchanged from round 12/14 best config)
#define DEC_TLOAD(b0, b1, base)                                               \
    _Pragma("unroll")                                                         \
    for (int i = 0; i < 5; ++i) {                                             \
        b0[i] = *(const float2*)(tg0 + (base) + 2 * i);                       \
        b1[i] = *(const float2*)(tg1 + (base) + 2 * i);                       \
    }
#define DEC_LCOMP(b0, b1, base)                                               \
    _Pragma("unroll")                                                         \
    for (int i = 0; i < 10; ++i) {                                            \
        int ff = (base) + i;                                                  \
        float dma, dmb, dla, dlb;                                             \
        dot16p_2(p2a, p2b, &wh3[ff * 16], dma, dmb);                          \
        dot16p_2(p2a, p2b, &wh3[(50 + ff) * 16], dla, dlb);                   \
        float xma = wd[256 + ff] + dma, xmb = wd[256 + ff] + dmb;             \
        float cla = clamp6(wd[256 + 50 + ff] + dla);                          \
        float clb = clamp6(wd[256 + 50 + ff] + dlb);                          \
        float tva = (i & 1) ? b0[i >> 1].y : b0[i >> 1].x;                    \
        float tvb = (i & 1) ? b1[i >> 1].y : b1[i >> 1].x;                    \
        float ua = (tva - xma) * __expf(-cla);                                \
        float ub = (tvb - xmb) * __expf(-clb);                                \
        lpa += -0.5f * ua * ua - cla - 0.91893853320467274f;                  \
        lpb += -0.5f * ub * ub - clb - 0.91893853320467274f;                  \
    }

__global__ __launch_bounds__(256) void dec_kernel(
    const float* __restrict__ zsb, const float* __restrict__ xs,
    const float* __restrict__ dcW1, const float* __restrict__ dcb1,
    const float* __restrict__ dcW2, const float* __restrict__ dcb2,
    const float* __restrict__ dcW3, const float* __restrict__ dcb3,
    float* __restrict__ acc)
{
    __shared__ __align__(16) float wd[356];
    __shared__ __align__(16) unsigned int wh2d[15 * 32];
    __shared__ __align__(16) unsigned int wh3[100 * 16];

    for (int i = threadIdx.x; i < 180; i += 256) wd[(i / 30) * 32 + (i % 30)] = dcW1[i];
    if (threadIdx.x < 30) wd[192 + threadIdx.x] = dcb1[threadIdx.x];
    if (threadIdx.x >= 32 && threadIdx.x < 62) wd[224 + threadIdx.x - 32] = dcb2[threadIdx.x - 32];
    for (int i = threadIdx.x; i < 100; i += 256) wd[256 + i] = dcb3[i];
    for (int i = threadIdx.x; i < 15 * 30; i += 256) {
        int p = i / 30, j = i % 30;
        wh2d[p * 32 + j] = packh2(dcW2[(2 * p) * 30 + j], dcW2[(2 * p + 1) * 30 + j]);
    }
    for (int i = threadIdx.x; i < 100 * 16; i += 256) {
        int ff = i / 16, p = i % 16;
        wh3[i] = (p < 15) ? packh2(dcW3[(2 * p) * 100 + ff], dcW3[(2 * p + 1) * 100 + ff]) : 0u;
    }
    __syncthreads();

    int t = threadIdx.x;
    size_t base = (size_t)blockIdx.x * 512;
    size_t s0 = base + t, s1 = base + t + 256;

    float za[6], zb[6];
    {
        const float* zp0 = zsb + s0 * 6;
        const float* zp1 = zsb + s1 * 6;
#pragma unroll
        for (int i = 0; i < 3; ++i) {
            float2 v0 = *(const float2*)(zp0 + 2 * i);
            float2 v1 = *(const float2*)(zp1 + 2 * i);
            za[2 * i] = v0.x; za[2 * i + 1] = v0.y;
            zb[2 * i] = v1.x; zb[2 * i + 1] = v1.y;
        }
    }

    float h1a[30], h1b[30];
#pragma unroll
    for (int j = 0; j < 30; ++j) { h1a[j] = wd[192 + j]; h1b[j] = h1a[j]; }
#pragma unroll
    for (int i = 0; i < 6; ++i) {
        float via = za[i], vib = zb[i];
        const float* wrow = &wd[i * 32];
#pragma unroll
        for (int q = 0; q < 7; ++q) {
            float4 wv = *(const float4*)(wrow + 4 * q);
            h1a[4 * q + 0] = fmaf(via, wv.x, h1a[4 * q + 0]);
            h1b[4 * q + 0] = fmaf(vib, wv.x, h1b[4 * q + 0]);
            h1a[4 * q + 1] = fmaf(via, wv.y, h1a[4 * q + 1]);
            h1b[4 * q + 1] = fmaf(vib, wv.y, h1b[4 * q + 1]);
            h1a[4 * q + 2] = fmaf(via, wv.z, h1a[4 * q + 2]);
            h1b[4 * q + 2] = fmaf(vib, wv.z, h1b[4 * q + 2]);
            h1a[4 * q + 3] = fmaf(via, wv.w, h1a[4 * q + 3]);
            h1b[4 * q + 3] = fmaf(vib, wv.w, h1b[4 * q + 3]);
        }
        float2 wt = *(const float2*)(wrow + 28);
        h1a[28] = fmaf(via, wt.x, h1a[28]);
        h1b[28] = fmaf(vib, wt.x, h1b[28]);
        h1a[29] = fmaf(via, wt.y, h1a[29]);
        h1b[29] = fmaf(vib, wt.y, h1b[29]);
    }
#pragma unroll
    for (int j = 0; j < 30; ++j) { h1a[j] = sp_f(h1a[j]); h1b[j] = sp_f(h1b[j]); }

    unsigned int p1a[15], p1b[15];
#pragma unroll
    for (int p = 0; p < 15; ++p) {
        p1a[p] = packh2(h1a[2 * p], h1a[2 * p + 1]);
        p1b[p] = packh2(h1b[2 * p], h1b[2 * p + 1]);
    }
    float h2a[30], h2b[30];
#pragma unroll
    for (int j = 0; j < 30; ++j) { h2a[j] = wd[224 + j]; h2b[j] = h2a[j]; }
#pragma unroll
    for (int p = 0; p < 15; ++p)
        rowd2(h2a, h2b, &wh2d[p * 32], p1a[p], p1b[p]);
#pragma unroll
    for (int j = 0; j < 30; ++j) { h2a[j] = sp_f(h2a[j]); h2b[j] = sp_f(h2b[j]); }

    unsigned int p2a[16], p2b[16];
#pragma unroll
    for (int p = 0; p < 15; ++p) {
        p2a[p] = packh2(h2a[2 * p], h2a[2 * p + 1]);
        p2b[p] = packh2(h2b[2 * p], h2b[2 * p + 1]);
    }
    p2a[15] = 0u; p2b[15] = 0u;

    const float* tg0 = xs + s0 * 150 + 100;
    const float* tg1 = xs + s1 * 150 + 100;
    float lpa = 0.f, lpb = 0.f;
    float2 TA0[5], TA1[5], TB0[5], TB1[5];
    DEC_TLOAD(TA0, TA1, 0)
    DEC_TLOAD(TB0, TB1, 10)
    DEC_LCOMP(TA0, TA1, 0)
    DEC_TLOAD(TA0, TA1, 20)
    DEC_LCOMP(TB0, TB1, 10)
    DEC_TLOAD(TB0, TB1, 30)
    DEC_LCOMP(TA0, TA1, 20)
    DEC_TLOAD(TA0, TA1, 40)
    DEC_LCOMP(TB0, TB1, 30)
    DEC_LCOMP(TA0, TA1, 40)

    float lpacc = lpa + lpb;
#pragma unroll
    for (int mm = 1; mm <= 32; mm <<= 1) lpacc += __shfl_xor(lpacc, mm);
    __shared__ float red[4];
    if ((threadIdx.x & 63) == 0) red[threadIdx.x >> 6] = lpacc;
    __syncthreads();
    if (threadIdx.x == 0) atomicAdd(&acc[0], red[0] + red[1] + red[2] + red[3]);
}

__global__ void final_kernel(const float* __restrict__ acc, float* __restrict__ out)
{
    out[0] = acc[0] * (1.f / (float)Bn);
    out[1] = (acc[1] + acc[2]) * (1.f / (float)Bn);
}

// --------------------------------------------------------------------- launch
extern "C" void kernel_launch(void* const* d_in, const int* in_sizes, int n_in,
                              void* d_out, int out_size, void* d_ws, size_t ws_size,
                              hipStream_t stream)
{
    const float* xs   = (const float*)d_in[0];
    const float* ts   = (const float*)d_in[1];
    const float* eps0 = (const float*)d_in[2];
    const float* dW   = (const float*)d_in[3];
    const float* eW1  = (const float*)d_in[4];
    const float* eb1  = (const float*)d_in[5];
    const float* eW2  = (const float*)d_in[6];
    const float* eb2  = (const float*)d_in[7];
    const float* eW3  = (const float*)d_in[8];
    const float* eb3  = (const float*)d_in[9];
    const float* dcW1 = (const float*)d_in[10];
    const float* dcb1 = (const float*)d_in[11];
    const float* dcW2 = (const float*)d_in[12];
    const float* dcb2 = (const float*)d_in[13];
    const float* dcW3 = (const float*)d_in[14];
    const float* dcb3 = (const float*)d_in[15];
    const float* fW1  = (const float*)d_in[16];
    const float* fb1  = (const float*)d_in[17];
    const float* fW2  = (const float*)d_in[18];
    const float* fb2  = (const float*)d_in[19];
    const float* hW1  = (const float*)d_in[20];
    const float* hb1  = (const float*)d_in[21];
    const float* hW2  = (const float*)d_in[22];
    const float* hb2  = (const float*)d_in[23];
    const float* gW1  = (const float*)d_in[24];
    const float* gb1  = (const float*)d_in[25];
    const float* gW2  = (const float*)d_in[26];
    const float* gb2  = (const float*)d_in[27];
    const float* pm   = (const float*)d_in[28];
    const float* ps   = (const float*)d_in[29];

    float* ws  = (float*)d_ws;
    float* acc = ws;                    // [0]=S_lp, [1]=S_kl, [2]=S_path
    float* ctx = ws + 16;               // T*B*3 = 614400
    float* qm  = ctx + 614400;          // B*6
    float* qs  = qm + 12288;            // B*6
    float* zs  = qs + 12288;            // T*B*6 = 1228800
    float* out = (float*)d_out;

    hipMemsetAsync(acc, 0, 16 * sizeof(float), stream);
    enc_kernel<<<400, 256, 0, stream>>>(xs, eW1, eb1, eW2, eb2, eW3, eb3, ctx, qm, qs);
    scan_kernel<<<1024, 128, 0, stream>>>(ts, dW, fW1, fb1, fW2, fb2, hW1, hb1,
                                          hW2, hb2, gW1, gb1, gW2, gb2, ctx,
                                          qm, qs, eps0, pm, ps, zs, acc);
    dec_kernel<<<400, 256, 0, stream>>>(zs, xs, dcW1, dcb1, dcW2, dcb2, dcW3, dcb3, acc);
    final_kernel<<<1, 1, 0, stream>>>(acc, out);
}

// Round 16
// 244.089 us; speedup vs baseline: 1.0376x; 1.0376x over previous
//
#include <hip/hip_runtime.h>
#include <hip/hip_bf16.h>
#include <math.h>

#define Tn 100
#define Bn 2048

typedef int v2i __attribute__((ext_vector_type(2)));
typedef _Float16 h2v __attribute__((ext_vector_type(2)));

__device__ __forceinline__ float sp_f(float x) {
    // jax.nn.softplus(x) = max(x,0) + log1p(exp(-|x|))
    float e = __expf(-fabsf(x));
    return fmaxf(x, 0.f) + __logf(1.f + e);
}
__device__ __forceinline__ float clamp6(float x) {
    return fminf(fmaxf(x, -6.f), 6.f);
}
// pack two f32 into half2 (RNE via casts)
__device__ __forceinline__ unsigned int packh2(float a, float b) {
    h2v h; h.x = (_Float16)a; h.y = (_Float16)b;
    return __builtin_bit_cast(unsigned int, h);
}
// dot2: a.x*b.x + a.y*b.y + c  (f32 accumulate)
__device__ __forceinline__ float dot2f(unsigned int a, unsigned int b, float c) {
#if __has_builtin(__builtin_amdgcn_fdot2)
    return __builtin_amdgcn_fdot2(__builtin_bit_cast(h2v, a),
                                  __builtin_bit_cast(h2v, b), c, false);
#else
    h2v ha = __builtin_bit_cast(h2v, a), hb = __builtin_bit_cast(h2v, b);
    return fmaf((float)ha.y, (float)hb.y, fmaf((float)ha.x, (float)hb.x, c));
#endif
}

// DPP cross-lane (pure VALU).
__device__ __forceinline__ float dpp_xor1(float x) {
    return __int_as_float(__builtin_amdgcn_mov_dpp(__float_as_int(x), 0xB1, 0xF, 0xF, 1));
}
__device__ __forceinline__ float dpp_xor2(float x) {
    return __int_as_float(__builtin_amdgcn_mov_dpp(__float_as_int(x), 0x4E, 0xF, 0xF, 1));
}
__device__ __forceinline__ float dpp_hmirror(float x) {
    return __int_as_float(__builtin_amdgcn_mov_dpp(__float_as_int(x), 0x141, 0xF, 0xF, 1));
}
__device__ __forceinline__ float dpp_ror8(float x) {
    return __int_as_float(__builtin_amdgcn_mov_dpp(__float_as_int(x), 0x128, 0xF, 0xF, 1));
}
template <int OFF>
__device__ __forceinline__ float swz(float x) {
    return __int_as_float(__builtin_amdgcn_ds_swizzle(__float_as_int(x), OFF));
}
__device__ __forceinline__ float xor16_sum(float x) {
#if __has_builtin(__builtin_amdgcn_permlane16_swap)
    v2i r = __builtin_amdgcn_permlane16_swap(__float_as_int(x), __float_as_int(x), false, false);
    return __int_as_float(r[0]) + __int_as_float(r[1]);
#else
    return x + swz<0x401F>(x);
#endif
}
__device__ __forceinline__ float other_half(float x) {
#if __has_builtin(__builtin_amdgcn_permlane32_swap)
    v2i r = __builtin_amdgcn_permlane32_swap(__float_as_int(x), __float_as_int(x), false, false);
    return (__int_as_float(r[0]) + __int_as_float(r[1])) - x;
#else
    return __shfl_xor(x, 32);
#endif
}

// f16 pair-dot row: h{a,b}[0..29] = dot2(x{a,b}, wrow[j], h{a,b}[j])
__device__ __forceinline__ void rowd2(float* ha, float* hb, const unsigned int* wrow,
                                      unsigned int xa, unsigned int xb) {
#pragma unroll
    for (int q = 0; q < 7; ++q) {
        uint4 wv = *(const uint4*)(wrow + 4 * q);
        ha[4 * q + 0] = dot2f(xa, wv.x, ha[4 * q + 0]);
        hb[4 * q + 0] = dot2f(xb, wv.x, hb[4 * q + 0]);
        ha[4 * q + 1] = dot2f(xa, wv.y, ha[4 * q + 1]);
        hb[4 * q + 1] = dot2f(xb, wv.y, hb[4 * q + 1]);
        ha[4 * q + 2] = dot2f(xa, wv.z, ha[4 * q + 2]);
        hb[4 * q + 2] = dot2f(xb, wv.z, hb[4 * q + 2]);
        ha[4 * q + 3] = dot2f(xa, wv.w, ha[4 * q + 3]);
        hb[4 * q + 3] = dot2f(xb, wv.w, hb[4 * q + 3]);
    }
    uint2 wt = *(const uint2*)(wrow + 28);
    ha[28] = dot2f(xa, wt.x, ha[28]);
    hb[28] = dot2f(xb, wt.x, hb[28]);
    ha[29] = dot2f(xa, wt.y, ha[29]);
    hb[29] = dot2f(xb, wt.y, hb[29]);
}
// fp32 dual dot30 (for small fp32 layers)
__device__ __forceinline__ void dot30_2(const float* ha, const float* hb,
                                        const float* wrow, float& ra, float& rb) {
    float a0 = 0.f, a1 = 0.f, b0 = 0.f, b1 = 0.f;
#pragma unroll
    for (int q = 0; q < 7; ++q) {
        float4 wv = *(const float4*)(wrow + 4 * q);
        a0 = fmaf(ha[4 * q + 0], wv.x, a0);
        b0 = fmaf(hb[4 * q + 0], wv.x, b0);
        a1 = fmaf(ha[4 * q + 1], wv.y, a1);
        b1 = fmaf(hb[4 * q + 1], wv.y, b1);
        a0 = fmaf(ha[4 * q + 2], wv.z, a0);
        b0 = fmaf(hb[4 * q + 2], wv.z, b0);
        a1 = fmaf(ha[4 * q + 3], wv.w, a1);
        b1 = fmaf(hb[4 * q + 3], wv.w, b1);
    }
    float2 wt = *(const float2*)(wrow + 28);
    a0 = fmaf(ha[28], wt.x, a0);
    b0 = fmaf(hb[28], wt.x, b0);
    a1 = fmaf(ha[29], wt.y, a1);
    b1 = fmaf(hb[29], wt.y, b1);
    ra = a0 + a1; rb = b0 + b1;
}
// f16 16-pair dual dot (for dec L3; pair 15 must be zero)
__device__ __forceinline__ void dot16p_2(const unsigned int* pa, const unsigned int* pb,
                                         const unsigned int* wrow, float& ra, float& rb) {
    float a0 = 0.f, a1 = 0.f, b0 = 0.f, b1 = 0.f;
#pragma unroll
    for (int q = 0; q < 4; ++q) {
        uint4 wv = *(const uint4*)(wrow + 4 * q);
        a0 = dot2f(pa[4 * q + 0], wv.x, a0);
        b0 = dot2f(pb[4 * q + 0], wv.x, b0);
        a1 = dot2f(pa[4 * q + 1], wv.y, a1);
        b1 = dot2f(pb[4 * q + 1], wv.y, b1);
        a0 = dot2f(pa[4 * q + 2], wv.z, a0);
        b0 = dot2f(pb[4 * q + 2], wv.z, b0);
        a1 = dot2f(pa[4 * q + 3], wv.w, a1);
        b1 = dot2f(pb[4 * q + 3], wv.w, b1);
    }
    ra = a0 + a1; rb = b0 + b1;
}

// ---------------------------------------------------------------- encoder
// M=2 samples/thread. L1/L2 in packed f16 (pairs over input idx), L3 fp32.
#define ENC_LOAD2(b0, b1, base)                                               \
    _Pragma("unroll")                                                         \
    for (int i = 0; i < 5; ++i) {                                             \
        b0[i] = *(const float2*)(x0 + (base) + 2 * i);                        \
        b1[i] = *(const float2*)(x1 + (base) + 2 * i);                        \
    }
#define ENC_COMP2(b0, b1, pb)                                                 \
    _Pragma("unroll")                                                         \
    for (int i = 0; i < 5; ++i) {                                             \
        unsigned int xa = packh2(b0[i].x, b0[i].y);                           \
        unsigned int xb = packh2(b1[i].x, b1[i].y);                           \
        rowd2(h1a, h1b, &wh1[((pb) + i) * 32], xa, xb);                       \
    }

__global__ __launch_bounds__(256) void enc_kernel(
    const float* __restrict__ xs,
    const float* __restrict__ eW1, const float* __restrict__ eb1,
    const float* __restrict__ eW2, const float* __restrict__ eb2,
    const float* __restrict__ eW3, const float* __restrict__ eb3,
    float* __restrict__ ctx, float* __restrict__ qm, float* __restrict__ qs)
{
    __shared__ __align__(16) unsigned int wh1[75 * 32];
    __shared__ __align__(16) unsigned int wh2[15 * 32];
    __shared__ __align__(16) float wf[555];

    for (int i = threadIdx.x; i < 75 * 30; i += 256) {
        int p = i / 30, j = i % 30;
        wh1[p * 32 + j] = packh2(eW1[(2 * p) * 30 + j], eW1[(2 * p + 1) * 30 + j]);
    }
    for (int i = threadIdx.x; i < 15 * 30; i += 256) {
        int p = i / 30, j = i % 30;
        wh2[p * 32 + j] = packh2(eW2[(2 * p) * 30 + j], eW2[(2 * p + 1) * 30 + j]);
    }
    if (threadIdx.x < 30) wf[threadIdx.x] = eb1[threadIdx.x];
    if (threadIdx.x >= 32 && threadIdx.x < 62) wf[30 + threadIdx.x - 32] = eb2[threadIdx.x - 32];
    for (int i = threadIdx.x; i < 90; i += 256) {        // wc3[o][j2] = eW3[j2][12+o]
        int o = i / 30, j2 = i % 30;
        wf[60 + o * 32 + j2] = eW3[j2 * 15 + 12 + o];
    }
    for (int i = threadIdx.x; i < 360; i += 256) {       // wcq[o][j2] = eW3[j2][o]
        int o = i / 30, j2 = i % 30;
        wf[156 + o * 32 + j2] = eW3[j2 * 15 + o];
    }
    if (threadIdx.x >= 64 && threadIdx.x < 79) wf[540 + threadIdx.x - 64] = eb3[threadIdx.x - 64];
    __syncthreads();

    int t = threadIdx.x;
    size_t base = (size_t)blockIdx.x * 512;
    size_t s0 = base + t, s1 = base + t + 256;
    const float* x0 = xs + s0 * 150;
    const float* x1 = xs + s1 * 150;

    float h1a[30], h1b[30];
#pragma unroll
    for (int j = 0; j < 30; ++j) { h1a[j] = wf[j]; h1b[j] = h1a[j]; }

    float2 A0[5], A1[5], B0[5], B1[5];
    ENC_LOAD2(A0, A1, 0)
    ENC_LOAD2(B0, B1, 10)
    int fb = 0;
#pragma unroll 1
    for (int it = 0; it < 6; ++it) {
        ENC_COMP2(A0, A1, fb / 2)
        ENC_LOAD2(A0, A1, fb + 20)
        ENC_COMP2(B0, B1, fb / 2 + 5)
        ENC_LOAD2(B0, B1, fb + 30)
        fb += 20;
    }
    ENC_COMP2(A0, A1, 60)
    ENC_LOAD2(A0, A1, 140)
    ENC_COMP2(B0, B1, 65)
    ENC_COMP2(A0, A1, 70)

#pragma unroll
    for (int j = 0; j < 30; ++j) { h1a[j] = sp_f(h1a[j]); h1b[j] = sp_f(h1b[j]); }

    // pack h1 pairs for L2
    unsigned int p1a[15], p1b[15];
#pragma unroll
    for (int p = 0; p < 15; ++p) {
        p1a[p] = packh2(h1a[2 * p], h1a[2 * p + 1]);
        p1b[p] = packh2(h1b[2 * p], h1b[2 * p + 1]);
    }
    float h2a[30], h2b[30];
#pragma unroll
    for (int j = 0; j < 30; ++j) { h2a[j] = wf[30 + j]; h2b[j] = h2a[j]; }
#pragma unroll
    for (int p = 0; p < 15; ++p)
        rowd2(h2a, h2b, &wh2[p * 32], p1a[p], p1b[p]);
#pragma unroll
    for (int j = 0; j < 30; ++j) { h2a[j] = sp_f(h2a[j]); h2b[j] = sp_f(h2b[j]); }

    // L3 ctx (fp32)
    float oa3[3], ob3[3];
#pragma unroll
    for (int o = 0; o < 3; ++o) {
        float ra, rb;
        dot30_2(h2a, h2b, &wf[60 + o * 32], ra, rb);
        oa3[o] = wf[540 + 12 + o] + ra;
        ob3[o] = wf[540 + 12 + o] + rb;
    }
    float* cp0 = ctx + s0 * 3;
    cp0[0] = oa3[0]; cp0[1] = oa3[1]; cp0[2] = oa3[2];
    float* cp1 = ctx + s1 * 3;
    cp1[0] = ob3[0]; cp1[1] = ob3[1]; cp1[2] = ob3[2];

    if (blockIdx.x < 4) {   // samples < 2048: tt == 0 -> qz0 stats (fp32)
#pragma unroll
        for (int o = 0; o < 12; ++o) {
            float ra, rb;
            dot30_2(h2a, h2b, &wf[156 + o * 32], ra, rb);
            float va = wf[540 + o] + ra, vb = wf[540 + o] + rb;
            if (o < 6) { qm[s0 * 6 + o] = va; qm[s1 * 6 + o] = vb; }
            else       { qs[s0 * 6 + o - 6] = va; qs[s1 * 6 + o - 6] = vb; }
        }
    }
}

// ------------------------------------------------------------------- SDE scan
// Best-measured structure (round 12): 2-wave asymmetric slim tails.
__global__ __launch_bounds__(128, 4) void scan_kernel(
    const float* __restrict__ ts, const float* __restrict__ dWall,
    const float* __restrict__ fW1, const float* __restrict__ fb1,
    const float* __restrict__ fW2, const float* __restrict__ fb2,
    const float* __restrict__ hW1, const float* __restrict__ hb1,
    const float* __restrict__ hW2, const float* __restrict__ hb2,
    const float* __restrict__ gW1, const float* __restrict__ gb1,
    const float* __restrict__ gW2, const float* __restrict__ gb2,
    const float* __restrict__ ctx,
    const float* __restrict__ qm, const float* __restrict__ qs,
    const float* __restrict__ eps0, const float* __restrict__ pm,
    const float* __restrict__ ps,
    float* __restrict__ zsb, float* __restrict__ acc)
{
    int tid = threadIdx.x;
    int lane = tid & 63;
    int b = blockIdx.x;
    bool isA = tid < 64;

    __shared__ float sRec[99 * 12];
    __shared__ float exF[2][12];      // [0..5]=fvv, [6..11]=dfh
    __shared__ float exG[2][8];       // [0..5]=g

    for (int i = tid; i < 99 * 3; i += 128) {
        int k = i / 3, e = i % 3;
        float2 v = *(const float2*)(dWall + ((size_t)k * Bn + b) * 6 + e * 2);
        *(float2*)&sRec[k * 12 + e * 2] = v;
    }
    for (int i = tid; i < 99 * 3; i += 128) {
        int k = i / 3, e = i % 3;
        sRec[k * 12 + 6 + e] = ctx[((size_t)(k + 1) * Bn + b) * 3 + e];
    }
    for (int i = tid; i < 99; i += 128) {
        float t0 = ts[i], t1 = ts[i + 1];
        sRec[i * 12 + 9]  = 0.f;
        sRec[i * 12 + 10] = t0;
        sRec[i * 12 + 11] = t1 - t0;
    }

    float z[6];
    float zq = 0.f;
    float wl1[10], b1w, wl2[6], fb2v[6], hb2v[6];
    float gwa[4], gwb[4], gw2v[4], gbb[4], gb2v = 0.f, wselq = 0.f;
    int dL = 0;

    if (isA) {
        bool lower = lane < 32;
        int j = lane & 31;
        int jc = (j < 30) ? j : 29;
        bool jvalid = (j < 30);
#pragma unroll
        for (int i = 0; i < 10; ++i)
            wl1[i] = lower ? fW1[i * 30 + jc] : (i < 7 ? hW1[i * 30 + jc] : 0.f);
        b1w = lower ? fb1[jc] : hb1[jc];
#pragma unroll
        for (int d = 0; d < 6; ++d)
            wl2[d] = jvalid ? (lower ? fW2[jc * 6 + d] : hW2[jc * 6 + d]) : 0.f;
#pragma unroll
        for (int d = 0; d < 6; ++d) { fb2v[d] = fb2[d]; hb2v[d] = hb2[d]; }
#pragma unroll
        for (int d = 0; d < 6; ++d) {
            float m = qm[b * 6 + d];
            float sq = __expf(clamp6(qs[b * 6 + d]));
            z[d] = fmaf(sq, eps0[b * 6 + d], m);
        }
        if (tid == 0) {
            float* zp = zsb + (size_t)b * 6;
            *(float2*)(zp)     = make_float2(z[0], z[1]);
            *(float2*)(zp + 2) = make_float2(z[2], z[3]);
            *(float2*)(zp + 4) = make_float2(z[4], z[5]);
        }
    } else {
        int dL8 = lane >> 3;
        dL = (dL8 < 6) ? dL8 : 0;
        wselq = (dL8 < 6) ? 0.0625f : 0.f;
        int s = lane & 7;
#pragma unroll
        for (int u = 0; u < 4; ++u) {
            int jj = s + 8 * u;
            bool ok = (dL8 < 6) && (jj < 30);
            gwa[u]  = ok ? gW1[dL * 60 + jj] : 0.f;
            gwb[u]  = ok ? gW1[dL * 60 + 30 + jj] : 0.f;
            gw2v[u] = ok ? gW2[dL * 30 + jj] : 0.f;
            gbb[u]  = ok ? gb1[dL * 30 + jj] : 0.f;
        }
        gb2v = gb2[dL];
        {
            float m = qm[b * 6 + dL];
            float sq = __expf(clamp6(qs[b * 6 + dL]));
            zq = fmaf(sq, eps0[b * 6 + dL], m);
        }
        if (tid == 64) {
            float klsum = 0.f;
#pragma unroll
            for (int d = 0; d < 6; ++d) {
                float m = qm[b * 6 + d];
                float sq = __expf(clamp6(qs[b * 6 + d]));
                float spz = __expf(clamp6(ps[d]));
                float dm = m - pm[d];
                klsum += __logf(spz / sq) + (sq * sq + dm * dm) / (2.f * spz * spz) - 0.5f;
            }
            atomicAdd(&acc[1], klsum);
        }
    }

    __syncthreads();

    float pacc = 0.f;

    for (int k = 0; k < Tn - 1; ++k) {
        int kb = k & 1;

        if (isA) {
            float4 r0 = *(float4*)&sRec[k * 12];
            float4 r1 = *(float4*)&sRec[k * 12 + 4];
            float4 r2 = *(float4*)&sRec[k * 12 + 8];
            float t = r2.z, dt = r2.w;

            float a = fmaf(t, wl1[0], b1w);
#pragma unroll
            for (int i = 0; i < 6; ++i) a = fmaf(z[i], wl1[1 + i], a);
            a = fmaf(r1.z, wl1[7], a);
            a = fmaf(r1.w, wl1[8], a);
            a = fmaf(r2.x, wl1[9], a);
            float hid = sp_f(a);

            float pp[6];
#pragma unroll
            for (int d = 0; d < 6; ++d) pp[d] = hid * wl2[d];
#pragma unroll
            for (int d = 0; d < 6; ++d) pp[d] += dpp_xor1(pp[d]);
#pragma unroll
            for (int d = 0; d < 6; ++d) pp[d] += dpp_xor2(pp[d]);
#pragma unroll
            for (int d = 0; d < 6; ++d) pp[d] += dpp_hmirror(pp[d]);
#pragma unroll
            for (int d = 0; d < 6; ++d) pp[d] += dpp_ror8(pp[d]);
#pragma unroll
            for (int d = 0; d < 6; ++d) pp[d] = xor16_sum(pp[d]);
            float fvv[6], dfh[6];
            bool lower = lane < 32;
#pragma unroll
            for (int d = 0; d < 6; ++d) {
                float oth = other_half(pp[d]);
                float fsum = lower ? pp[d] : oth;
                float hsum = lower ? oth : pp[d];
                fvv[d] = fsum + fb2v[d];
                dfh[d] = fvv[d] - (hsum + hb2v[d]);
            }
            if (lane == 0) {
                *(float4*)&exF[kb][0] = make_float4(fvv[0], fvv[1], fvv[2], fvv[3]);
                *(float4*)&exF[kb][4] = make_float4(fvv[4], fvv[5], dfh[0], dfh[1]);
                *(float4*)&exF[kb][8] = make_float4(dfh[2], dfh[3], dfh[4], dfh[5]);
            }

            __syncthreads();

            float4 g03 = *(float4*)&exG[kb][0];
            float2 g45 = *(float2*)&exG[kb][4];
            float gl[6] = { g03.x, g03.y, g03.z, g03.w, g45.x, g45.y };
            float dwv[6] = { r0.x, r0.y, r0.z, r0.w, r1.x, r1.y };
#pragma unroll
            for (int d = 0; d < 6; ++d)
                z[d] = fmaf(gl[d], dwv[d], fmaf(fvv[d], dt, z[d]));

            if (tid == 0) {
                float* zp = zsb + ((size_t)(k + 1) * Bn + b) * 6;
                *(float2*)(zp)     = make_float2(z[0], z[1]);
                *(float2*)(zp + 2) = make_float2(z[2], z[3]);
                *(float2*)(zp + 4) = make_float2(z[4], z[5]);
            }
        } else {
            float2 tdt = *(float2*)&sRec[k * 12 + 10];
            float t = tdt.x, dt = tdt.y;
            float dwq = sRec[k * 12 + dL];

            float ga = 0.f;
#pragma unroll
            for (int u = 0; u < 4; ++u) {
                float pre = fmaf(t, gwa[u], gbb[u]);
                pre = fmaf(zq, gwb[u], pre);
                ga = fmaf(sp_f(pre), gw2v[u], ga);
            }
            ga += dpp_xor1(ga);
            ga += dpp_xor2(ga);
            ga += dpp_hmirror(ga);
            float gacc = ga + gb2v;
            float e = __expf(-gacc);
            float rg = 1.f + e;
            float gval = __builtin_amdgcn_rcpf(rg);
            if ((lane & 7) == 0 && (lane >> 3) < 6)
                exG[kb][dL] = gval;

            __syncthreads();

            float fq  = exF[kb][dL];
            float dfq = exF[kb][6 + dL];
            float u = dfq * rg;
            pacc = fmaf(wselq * dt, u * u, pacc);
            zq = fmaf(gval, dwq, fmaf(fq, dt, zq));
        }
    }
    if (!isA) {
#pragma unroll
        for (int mm = 1; mm <= 32; mm <<= 1) pacc += __shfl_xor(pacc, mm);
        if (tid == 64) atomicAdd(&acc[2], pacc);
    }
}

// ------------------------------------------------------ decoder + likelihood
// M=2; L1 fp32, L2 f16-pairs, L3 f16-pairs (16-pair rows, pad 0).
#define DEC_TLOAD(b0, b1, base)                                               \
    _Pragma("unroll")                                                         \
    for (int i = 0; i < 5; ++i) {                                             \
        b0[i] = *(const float2*)(tg0 + (base) + 2 * i);                       \
        b1[i] = *(const float2*)(tg1 + (base) + 2 * i);                       \
    }
#define DEC_LCOMP(b0, b1, base)                                               \
    _Pragma("unroll")                                                         \
    for (int i = 0; i < 10; ++i) {                                            \
        int ff = (base) + i;                                                  \
        float dma, dmb, dla, dlb;                                             \
        dot16p_2(p2a, p2b, &wh3[ff * 16], dma, dmb);                          \
        dot16p_2(p2a, p2b, &wh3[(50 + ff) * 16], dla, dlb);                   \
        float xma = wd[256 + ff] + dma, xmb = wd[256 + ff] + dmb;             \
        float cla = clamp6(wd[256 + 50 + ff] + dla);                          \
        float clb = clamp6(wd[256 + 50 + ff] + dlb);                          \
        float tva = (i & 1) ? b0[i >> 1].y : b0[i >> 1].x;                    \
        float tvb = (i & 1) ? b1[i >> 1].y : b1[i >> 1].x;                    \
        float ua = (tva - xma) * __expf(-cla);                                \
        float ub = (tvb - xmb) * __expf(-clb);                                \
        lpa += -0.5f * ua * ua - cla - 0.91893853320467274f;                  \
        lpb += -0.5f * ub * ub - clb - 0.91893853320467274f;                  \
    }

__global__ __launch_bounds__(256) void dec_kernel(
    const float* __restrict__ zsb, const float* __restrict__ xs,
    const float* __restrict__ dcW1, const float* __restrict__ dcb1,
    const float* __restrict__ dcW2, const float* __restrict__ dcb2,
    const float* __restrict__ dcW3, const float* __restrict__ dcb3,
    float* __restrict__ acc)
{
    __shared__ __align__(16) float wd[356];
    __shared__ __align__(16) unsigned int wh2d[15 * 32];
    __shared__ __align__(16) unsigned int wh3[100 * 16];

    for (int i = threadIdx.x; i < 180; i += 256) wd[(i / 30) * 32 + (i % 30)] = dcW1[i];
    if (threadIdx.x < 30) wd[192 + threadIdx.x] = dcb1[threadIdx.x];
    if (threadIdx.x >= 32 && threadIdx.x < 62) wd[224 + threadIdx.x - 32] = dcb2[threadIdx.x - 32];
    for (int i = threadIdx.x; i < 100; i += 256) wd[256 + i] = dcb3[i];
    for (int i = threadIdx.x; i < 15 * 30; i += 256) {
        int p = i / 30, j = i % 30;
        wh2d[p * 32 + j] = packh2(dcW2[(2 * p) * 30 + j], dcW2[(2 * p + 1) * 30 + j]);
    }
    for (int i = threadIdx.x; i < 100 * 16; i += 256) {
        int ff = i / 16, p = i % 16;
        wh3[i] = (p < 15) ? packh2(dcW3[(2 * p) * 100 + ff], dcW3[(2 * p + 1) * 100 + ff]) : 0u;
    }
    __syncthreads();

    int t = threadIdx.x;
    size_t base = (size_t)blockIdx.x * 512;
    size_t s0 = base + t, s1 = base + t + 256;

    float za[6], zb[6];
    {
        const float* zp0 = zsb + s0 * 6;
        const float* zp1 = zsb + s1 * 6;
#pragma unroll
        for (int i = 0; i < 3; ++i) {
            float2 v0 = *(const float2*)(zp0 + 2 * i);
            float2 v1 = *(const float2*)(zp1 + 2 * i);
            za[2 * i] = v0.x; za[2 * i + 1] = v0.y;
            zb[2 * i] = v1.x; zb[2 * i + 1] = v1.y;
        }
    }

    float h1a[30], h1b[30];
#pragma unroll
    for (int j = 0; j < 30; ++j) { h1a[j] = wd[192 + j]; h1b[j] = h1a[j]; }
#pragma unroll
    for (int i = 0; i < 6; ++i) {
        float via = za[i], vib = zb[i];
        const float* wrow = &wd[i * 32];
#pragma unroll
        for (int q = 0; q < 7; ++q) {
            float4 wv = *(const float4*)(wrow + 4 * q);
            h1a[4 * q + 0] = fmaf(via, wv.x, h1a[4 * q + 0]);
            h1b[4 * q + 0] = fmaf(vib, wv.x, h1b[4 * q + 0]);
            h1a[4 * q + 1] = fmaf(via, wv.y, h1a[4 * q + 1]);
            h1b[4 * q + 1] = fmaf(vib, wv.y, h1b[4 * q + 1]);
            h1a[4 * q + 2] = fmaf(via, wv.z, h1a[4 * q + 2]);
            h1b[4 * q + 2] = fmaf(vib, wv.z, h1b[4 * q + 2]);
            h1a[4 * q + 3] = fmaf(via, wv.w, h1a[4 * q + 3]);
            h1b[4 * q + 3] = fmaf(vib, wv.w, h1b[4 * q + 3]);
        }
        float2 wt = *(const float2*)(wrow + 28);
        h1a[28] = fmaf(via, wt.x, h1a[28]);
        h1b[28] = fmaf(vib, wt.x, h1b[28]);
        h1a[29] = fmaf(via, wt.y, h1a[29]);
        h1b[29] = fmaf(vib, wt.y, h1b[29]);
    }
#pragma unroll
    for (int j = 0; j < 30; ++j) { h1a[j] = sp_f(h1a[j]); h1b[j] = sp_f(h1b[j]); }

    unsigned int p1a[15], p1b[15];
#pragma unroll
    for (int p = 0; p < 15; ++p) {
        p1a[p] = packh2(h1a[2 * p], h1a[2 * p + 1]);
        p1b[p] = packh2(h1b[2 * p], h1b[2 * p + 1]);
    }
    float h2a[30], h2b[30];
#pragma unroll
    for (int j = 0; j < 30; ++j) { h2a[j] = wd[224 + j]; h2b[j] = h2a[j]; }
#pragma unroll
    for (int p = 0; p < 15; ++p)
        rowd2(h2a, h2b, &wh2d[p * 32], p1a[p], p1b[p]);
#pragma unroll
    for (int j = 0; j < 30; ++j) { h2a[j] = sp_f(h2a[j]); h2b[j] = sp_f(h2b[j]); }

    unsigned int p2a[16], p2b[16];
#pragma unroll
    for (int p = 0; p < 15; ++p) {
        p2a[p] = packh2(h2a[2 * p], h2a[2 * p + 1]);
        p2b[p] = packh2(h2b[2 * p], h2b[2 * p + 1]);
    }
    p2a[15] = 0u; p2b[15] = 0u;

    const float* tg0 = xs + s0 * 150 + 100;   // xs[:,:,-1,:]
    const float* tg1 = xs + s1 * 150 + 100;
    float lpa = 0.f, lpb = 0.f;
    float2 TA0[5], TA1[5], TB0[5], TB1[5];
    DEC_TLOAD(TA0, TA1, 0)
    DEC_TLOAD(TB0, TB1, 10)
    DEC_LCOMP(TA0, TA1, 0)
    DEC_TLOAD(TA0, TA1, 20)
    DEC_LCOMP(TB0, TB1, 10)
    DEC_TLOAD(TB0, TB1, 30)
    DEC_LCOMP(TA0, TA1, 20)
    DEC_TLOAD(TA0, TA1, 40)
    DEC_LCOMP(TB0, TB1, 30)
    DEC_LCOMP(TA0, TA1, 40)

    float lpacc = lpa + lpb;
#pragma unroll
    for (int mm = 1; mm <= 32; mm <<= 1) lpacc += __shfl_xor(lpacc, mm);
    __shared__ float red[4];
    if ((threadIdx.x & 63) == 0) red[threadIdx.x >> 6] = lpacc;
    __syncthreads();
    if (threadIdx.x == 0) atomicAdd(&acc[0], red[0] + red[1] + red[2] + red[3]);
}

__global__ void final_kernel(const float* __restrict__ acc, float* __restrict__ out)
{
    out[0] = acc[0] * (1.f / (float)Bn);
    out[1] = (acc[1] + acc[2]) * (1.f / (float)Bn);
}

// --------------------------------------------------------------------- launch
extern "C" void kernel_launch(void* const* d_in, const int* in_sizes, int n_in,
                              void* d_out, int out_size, void* d_ws, size_t ws_size,
                              hipStream_t stream)
{
    const float* xs   = (const float*)d_in[0];
    const float* ts   = (const float*)d_in[1];
    const float* eps0 = (const float*)d_in[2];
    const float* dW   = (const float*)d_in[3];
    const float* eW1  = (const float*)d_in[4];
    const float* eb1  = (const float*)d_in[5];
    const float* eW2  = (const float*)d_in[6];
    const float* eb2  = (const float*)d_in[7];
    const float* eW3  = (const float*)d_in[8];
    const float* eb3  = (const float*)d_in[9];
    const float* dcW1 = (const float*)d_in[10];
    const float* dcb1 = (const float*)d_in[11];
    const float* dcW2 = (const float*)d_in[12];
    const float* dcb2 = (const float*)d_in[13];
    const float* dcW3 = (const float*)d_in[14];
    const float* dcb3 = (const float*)d_in[15];
    const float* fW1  = (const float*)d_in[16];
    const float* fb1  = (const float*)d_in[17];
    const float* fW2  = (const float*)d_in[18];
    const float* fb2  = (const float*)d_in[19];
    const float* hW1  = (const float*)d_in[20];
    const float* hb1  = (const float*)d_in[21];
    const float* hW2  = (const float*)d_in[22];
    const float* hb2  = (const float*)d_in[23];
    const float* gW1  = (const float*)d_in[24];
    const float* gb1  = (const float*)d_in[25];
    const float* gW2  = (const float*)d_in[26];
    const float* gb2  = (const float*)d_in[27];
    const float* pm   = (const float*)d_in[28];
    const float* ps   = (const float*)d_in[29];

    float* ws  = (float*)d_ws;
    float* acc = ws;                    // [0]=S_lp, [1]=S_kl, [2]=S_path
    float* ctx = ws + 16;               // T*B*3 = 614400
    float* qm  = ctx + 614400;          // B*6
    float* qs  = qm + 12288;            // B*6
    float* zs  = qs + 12288;            // T*B*6 = 1228800
    float* out = (float*)d_out;

    hipMemsetAsync(acc, 0, 16 * sizeof(float), stream);
    enc_kernel<<<400, 256, 0, stream>>>(xs, eW1, eb1, eW2, eb2, eW3, eb3, ctx, qm, qs);
    scan_kernel<<<2048, 128, 0, stream>>>(ts, dW, fW1, fb1, fW2, fb2, hW1, hb1,
                                          hW2, hb2, gW1, gb1, gW2, gb2, ctx,
                                          qm, qs, eps0, pm, ps, zs, acc);
    dec_kernel<<<400, 256, 0, stream>>>(zs, xs, dcW1, dcb1, dcW2, dcb2, dcW3, dcb3, acc);
    final_kernel<<<1, 1, 0, stream>>>(acc, out);
}